// Round 3
// baseline (9368.844 us; speedup 1.0000x reference)
//
#include <hip/hip_runtime.h>
#include <hip/hip_bf16.h>
#include <math.h>

// Problem dims (fixed by setup_inputs; n_layers is a device scalar -> hardcoded 8).
#define TQ    8192      // B*L tokens
#define DM    768       // model dim == ED
#define EMBD  512
#define NVOC  6400
#define LSEQ  2048
#define NBAT  4
#define NLAYER 8
#define DTR   48
#define CHUNK 64
#define NCH   (LSEQ/CHUNK)   // 32

// ---------------------------------------------------------------- GEMM (f32)
// C[M,N] = op(A) @ Bw(f32, KxN row-major), double-buffered LDS, float4 staged.
// GATHER: A rows gathered via rowidx (embedding).
// ASCALE: A element scaled by rscale[row]*cscale[k]  (fused rmsnorm).
// BIAS:   += bias[n].
// CONVSILU: epilogue applies silu(v*cw[col]+cb[col]) for col < DM (fused conv).
// K-split: blockIdx.z selects k-slice [z*kslice, (z+1)*kslice); C += z*slab.
#define BM 128
#define BN 128
#define BKK 16
#define LPAD 4
#define LDW (BM + LPAD)   // 132

template<bool GATHER, bool ASCALE, bool BIAS, bool CONVSILU>
__global__ __launch_bounds__(256)
void gemm_k(const float* __restrict__ A, int lda,
            const float* __restrict__ Bw,
            float* __restrict__ C, int ldc,
            int M, int N, int kslice,
            const int* __restrict__ rowidx,
            const float* __restrict__ rscale,
            const float* __restrict__ cscale,
            const float* __restrict__ bias,
            const float* __restrict__ cw, const float* __restrict__ cb,
            size_t slab)
{
    __shared__ float As[2][BKK][LDW];
    __shared__ float Bs[2][BKK][LDW];
    const int tid = threadIdx.x;
    const int tx = tid & 15;        // output cols tx*8..+8
    const int ty = tid >> 4;        // output rows ty*8..+8
    const int m0 = blockIdx.x * BM;
    const int n0 = blockIdx.y * BN;
    const int kbeg = blockIdx.z * kslice;
    float* Cz = C + (size_t)blockIdx.z * slab;

    // staging registers
    float4 ra[2], rb[2];
    // A-load decode: q = tid + 256*i -> row = q>>2 (0..127), kq = (q&3)*4
    const int ar  = tid >> 2;            // row for i=0 is ar, i=1 is ar+64
    const int akq = (tid & 3) * 4;
    // B-load decode: q = tid + 256*i -> kk = q>>5 (0..15), n4 = (q&31)*4
    const int bkk = tid >> 5;            // kk for i=0 is bkk, i=1 is bkk+8
    const int bn4 = (tid & 31) * 4;

#define LOADA(K0)                                                              \
    _Pragma("unroll")                                                          \
    for (int i = 0; i < 2; ++i) {                                              \
        int row = ar + i * 64;                                                 \
        int kg  = (K0) + akq;                                                  \
        long grow = GATHER ? (long)rowidx[m0 + row] : (long)(m0 + row);        \
        const float* p = A + grow * lda + kg;                                  \
        float4 v = *(const float4*)p;                                          \
        if (ASCALE) {                                                          \
            float rsv = rscale[m0 + row];                                      \
            v.x *= rsv * cscale[kg + 0]; v.y *= rsv * cscale[kg + 1];          \
            v.z *= rsv * cscale[kg + 2]; v.w *= rsv * cscale[kg + 3];          \
        }                                                                      \
        ra[i] = v;                                                             \
    }

#define WRITEA(B_)                                                             \
    _Pragma("unroll")                                                          \
    for (int i = 0; i < 2; ++i) {                                              \
        int row = ar + i * 64;                                                 \
        As[B_][akq + 0][row] = ra[i].x;                                        \
        As[B_][akq + 1][row] = ra[i].y;                                        \
        As[B_][akq + 2][row] = ra[i].z;                                        \
        As[B_][akq + 3][row] = ra[i].w;                                        \
    }

#define LOADB(K0)                                                              \
    _Pragma("unroll")                                                          \
    for (int i = 0; i < 2; ++i) {                                              \
        int kk = bkk + i * 8;                                                  \
        int ng = n0 + bn4;                                                     \
        const float* p = Bw + (long)((K0) + kk) * N + ng;                      \
        float4 v;                                                              \
        if (((N & 3) == 0) && (ng + 3 < N)) v = *(const float4*)p;             \
        else {                                                                 \
            v.x = (ng + 0 < N) ? p[0] : 0.f;                                   \
            v.y = (ng + 1 < N) ? p[1] : 0.f;                                   \
            v.z = (ng + 2 < N) ? p[2] : 0.f;                                   \
            v.w = (ng + 3 < N) ? p[3] : 0.f;                                   \
        }                                                                      \
        rb[i] = v;                                                             \
    }

#define WRITEB(B_)                                                             \
    _Pragma("unroll")                                                          \
    for (int i = 0; i < 2; ++i) {                                              \
        int kk = bkk + i * 8;                                                  \
        *(float4*)&Bs[B_][kk][bn4] = rb[i];                                    \
    }

    float acc[8][8];
#pragma unroll
    for (int i = 0; i < 8; ++i)
#pragma unroll
        for (int j = 0; j < 8; ++j) acc[i][j] = 0.f;

    // prologue: stage tile 0
    LOADA(kbeg); LOADB(kbeg);
    WRITEA(0);   WRITEB(0);

    const int nk = kslice / BKK;
    int cur = 0;
    for (int it = 0; it < nk; ++it) {
        __syncthreads();
        const bool more = (it + 1 < nk);
        if (more) {
            int k1 = kbeg + (it + 1) * BKK;
            LOADA(k1); LOADB(k1);
        }
#pragma unroll
        for (int kk = 0; kk < BKK; ++kk) {
            float a[8], b[8];
            *(float4*)&a[0] = *(const float4*)&As[cur][kk][ty * 8];
            *(float4*)&a[4] = *(const float4*)&As[cur][kk][ty * 8 + 4];
            *(float4*)&b[0] = *(const float4*)&Bs[cur][kk][tx * 8];
            *(float4*)&b[4] = *(const float4*)&Bs[cur][kk][tx * 8 + 4];
#pragma unroll
            for (int i = 0; i < 8; ++i)
#pragma unroll
                for (int j = 0; j < 8; ++j)
                    acc[i][j] = fmaf(a[i], b[j], acc[i][j]);
        }
        if (more) { WRITEA(cur ^ 1); WRITEB(cur ^ 1); }
        cur ^= 1;
    }

    // epilogue (M multiple of 128; guard N only)
#pragma unroll
    for (int i = 0; i < 8; ++i) {
        int row = m0 + ty * 8 + i;
#pragma unroll
        for (int j = 0; j < 8; ++j) {
            int col = n0 + tx * 8 + j;
            if (col < N) {
                float v = acc[i][j];
                if (BIAS) v += bias[col];
                if (CONVSILU && col < DM) {
                    float xc = fmaf(v, cw[col], cb[col]);
                    v = xc / (1.f + expf(-xc));
                }
                Cz[(long)row * ldc + col] = v;
            }
        }
    }
#undef LOADA
#undef WRITEA
#undef LOADB
#undef WRITEB
}

// -------------------------------------------------- rmsnorm row scale factors
__global__ __launch_bounds__(256)
void rowscale_k(const float* __restrict__ X, float* __restrict__ rs)
{
    int row  = blockIdx.x * 4 + (threadIdx.x >> 6);
    int lane = threadIdx.x & 63;
    const float4* xr = (const float4*)(X + (size_t)row * DM);
    float s = 0.f;
#pragma unroll
    for (int e = 0; e < 3; ++e) {            // DM/4 = 192 = 3*64
        float4 v = xr[lane + e * 64];
        s = fmaf(v.x, v.x, s); s = fmaf(v.y, v.y, s);
        s = fmaf(v.z, v.z, s); s = fmaf(v.w, v.w, s);
    }
#pragma unroll
    for (int off = 32; off > 0; off >>= 1) s += __shfl_down(s, off);
    if (lane == 0) rs[row] = rsqrtf(s * (1.0f / DM) + 1e-6f);
}

// -------- dt_proj + softplus -> delta ; a = exp(delta*A) ; bx = delta*xi*B_t
// dbc comes as 4 K-split partial slabs: P[s][TQ][50], summed here.
__global__ __launch_bounds__(256)
void dtfuse_k(const float* __restrict__ part,
              const float* __restrict__ Wdt, const float* __restrict__ bdt,
              const float* __restrict__ XZ, const float* __restrict__ Alog,
              float* __restrict__ a_out, float* __restrict__ bx_out)
{
    __shared__ float ds[16][52];
    int t0 = blockIdx.x * 16;
    for (int idx = threadIdx.x; idx < 16 * 50; idx += 256) {
        int tt = idx / 50, c = idx - tt * 50;
        size_t o = (size_t)(t0 + tt) * 50 + c;
        ds[tt][c] = part[o] + part[o + (size_t)TQ * 50]
                  + part[o + 2 * (size_t)TQ * 50] + part[o + 3 * (size_t)TQ * 50];
    }
    __syncthreads();
    for (int e0 = 0; e0 < DM; e0 += 256) {
        int e = e0 + threadIdx.x;
        float bias = bdt[e];
        float acc[16];
#pragma unroll
        for (int tt = 0; tt < 16; ++tt) acc[tt] = bias;
        for (int k = 0; k < DTR; ++k) {
            float w = Wdt[(size_t)k * DM + e];
#pragma unroll
            for (int tt = 0; tt < 16; ++tt) acc[tt] = fmaf(ds[tt][k], w, acc[tt]);
        }
        float An = -expf(Alog[e]);             // A = -exp(A_log), N=1
#pragma unroll
        for (int tt = 0; tt < 16; ++tt) {
            float delta = log1pf(expf(acc[tt]));   // softplus
            float a  = expf(delta * An);
            float xi = XZ[(size_t)(t0 + tt) * 1536 + e];
            float Bv = ds[tt][48];
            a_out [(size_t)(t0 + tt) * DM + e] = a;
            bx_out[(size_t)(t0 + tt) * DM + e] = delta * xi * Bv;
        }
    }
}

// ------------------------------------------------ chunked exact scan (3 pass)
__global__ __launch_bounds__(256)
void scan1_k(const float* __restrict__ a, const float* __restrict__ bx,
             float* __restrict__ Ac, float* __restrict__ Sc)
{
    int gid = blockIdx.x * 256 + threadIdx.x;   // [0, NBAT*NCH*DM)
    int e  = gid % DM;
    int bc = gid / DM;
    int ch = bc % NCH, b = bc / NCH;
    size_t base = ((size_t)(b * LSEQ + ch * CHUNK)) * DM + e;
    float A = 1.f, S = 0.f;
    for (int i = 0; i < CHUNK; ++i) {
        float av = a[base + (size_t)i * DM];
        float bv = bx[base + (size_t)i * DM];
        S = fmaf(av, S, bv);
        A *= av;
    }
    Ac[gid] = A; Sc[gid] = S;
}

__global__ __launch_bounds__(256)
void scan2_k(const float* __restrict__ Ac, const float* __restrict__ Sc,
             float* __restrict__ H0)
{
    int gid = blockIdx.x * 256 + threadIdx.x;   // [0, NBAT*DM)
    int e = gid % DM, b = gid / DM;
    float h = 0.f;
    for (int ch = 0; ch < NCH; ++ch) {
        size_t i = ((size_t)(b * NCH + ch)) * DM + e;
        H0[i] = h;                               // exclusive chunk-entry state
        h = fmaf(Ac[i], h, Sc[i]);
    }
}

__global__ __launch_bounds__(256)
void scan3_k(const float* __restrict__ a, float* __restrict__ hs,
             const float* __restrict__ H0)
{
    int gid = blockIdx.x * 256 + threadIdx.x;
    int e  = gid % DM;
    int bc = gid / DM;
    int ch = bc % NCH, b = bc / NCH;
    size_t base = ((size_t)(b * LSEQ + ch * CHUNK)) * DM + e;
    float h = H0[gid];
    for (int i = 0; i < CHUNK; ++i) {
        size_t idx = base + (size_t)i * DM;
        h = fmaf(a[idx], h, hs[idx]);           // hs currently holds bx
        hs[idx] = h;                            // in-place -> hidden state
    }
}

// -------------------- y = (hs*C_t + D*xi) * silu(z), written into Y (=a buf)
__global__ __launch_bounds__(256)
void yfuse_k(const float* __restrict__ hs, const float* __restrict__ XZ,
             const float* __restrict__ part, const float* __restrict__ Dp,
             float* __restrict__ Y)
{
    int t = blockIdx.x;
    size_t o = (size_t)t * 50 + 49;
    float Cv = part[o] + part[o + (size_t)TQ * 50]
             + part[o + 2 * (size_t)TQ * 50] + part[o + 3 * (size_t)TQ * 50];
    for (int e = threadIdx.x; e < DM; e += 256) {
        float xi = XZ[(size_t)t * 1536 + e];
        float z  = XZ[(size_t)t * 1536 + DM + e];
        float y  = fmaf(hs[(size_t)t * DM + e], Cv, Dp[e] * xi);
        float sz = z / (1.f + expf(-z));
        Y[(size_t)t * DM + e] = y * sz;
    }
}

// ---------------------------------------------------------------------------
extern "C" void kernel_launch(void* const* d_in, const int* in_sizes, int n_in,
                              void* d_out, int out_size, void* d_ws, size_t ws_size,
                              hipStream_t stream)
{
    const int*   tokens   = (const int*)  d_in[0];
    // d_in[1] = n_layers (device scalar) -> hardcoded NLAYER
    const float* emb_tab  = (const float*)d_in[2];
    const float* emb_proj = (const float*)d_in[3];
    const float* norm_w   = (const float*)d_in[4];
    const float* in_proj  = (const float*)d_in[5];
    const float* conv_w   = (const float*)d_in[6];
    const float* conv_b   = (const float*)d_in[7];
    const float* x_proj   = (const float*)d_in[8];
    const float* dt_proj  = (const float*)d_in[9];
    const float* dt_b     = (const float*)d_in[10];
    const float* A_log    = (const float*)d_in[11];
    const float* D_param  = (const float*)d_in[12];
    const float* out_proj = (const float*)d_in[13];
    const float* out_norm = (const float*)d_in[14];
    const float* head_w   = (const float*)d_in[15];
    const float* head_b   = (const float*)d_in[16];

    // ws layout (~26.4 MB, within the empirically-OK 27 MB): write-before-read
    float* Xbuf = (float*)d_ws;                     // TQ*DM
    float* rs   = Xbuf + (size_t)TQ * DM;           // TQ
    float* Ac   = rs + TQ;                          // NBAT*NCH*DM
    float* Sc   = Ac + (size_t)NBAT * NCH * DM;
    float* H0   = Sc + (size_t)NBAT * NCH * DM;

    // big scratch in d_out (f32 out = 209.7 MB; first ~107 MB used, all
    // write-before-read; head GEMM rewrites all of d_out at the end)
    float* XZ   = (float*)d_out;                    // TQ*1536
    float* Abuf = XZ + (size_t)TQ * 1536;           // TQ*DM (deltaA, later Y)
    float* BX   = Abuf + (size_t)TQ * DM;           // TQ*DM (bx -> hs in place)
    float* PART = BX + (size_t)TQ * DM;             // 4*TQ*50 (x_proj K-split)

    dim3 blk(256);

    // x = emb_table[tokens] @ emb_proj_w   (gathered GEMM, f32 out)
    gemm_k<true, false, false, false><<<dim3(TQ / BM, DM / BN, 1), blk, 0, stream>>>(
        emb_tab, EMBD, emb_proj, Xbuf, DM, TQ, DM, EMBD,
        tokens, nullptr, nullptr, nullptr, nullptr, nullptr, 0);

    for (int l = 0; l < NLAYER; ++l) {
        rowscale_k<<<TQ / 4, blk, 0, stream>>>(Xbuf, rs);
        // xz = rmsnorm(x)*norm_w @ in_proj_w, conv+silu fused on cols<DM
        gemm_k<false, true, false, true><<<dim3(TQ / BM, 1536 / BN, 1), blk, 0, stream>>>(
            Xbuf, DM, in_proj, XZ, 1536, TQ, 1536, DM,
            nullptr, rs, norm_w, nullptr, conv_w, conv_b, 0);
        // dbc partials = xi @ x_proj_w   (K split into 4 slices of 192)
        gemm_k<false, false, false, false><<<dim3(TQ / BM, 1, 4), blk, 0, stream>>>(
            XZ, 1536, x_proj, PART, 50, TQ, 50, DM / 4,
            nullptr, nullptr, nullptr, nullptr, nullptr, nullptr, (size_t)TQ * 50);
        dtfuse_k<<<TQ / 16, blk, 0, stream>>>(PART, dt_proj, dt_b, XZ, A_log, Abuf, BX);
        scan1_k<<<(NBAT * NCH * DM) / 256, blk, 0, stream>>>(Abuf, BX, Ac, Sc);
        scan2_k<<<(NBAT * DM) / 256, blk, 0, stream>>>(Ac, Sc, H0);
        scan3_k<<<(NBAT * NCH * DM) / 256, blk, 0, stream>>>(Abuf, BX, H0);
        yfuse_k<<<TQ, blk, 0, stream>>>(BX, XZ, PART, D_param, Abuf);
        // x' = y @ out_proj_w
        gemm_k<false, false, false, false><<<dim3(TQ / BM, DM / BN, 1), blk, 0, stream>>>(
            Abuf, DM, out_proj, Xbuf, DM, TQ, DM, DM,
            nullptr, nullptr, nullptr, nullptr, nullptr, nullptr, 0);
    }

    // out = rmsnorm(x)*out_norm_w @ head_w + head_b  (f32 out)
    rowscale_k<<<TQ / 4, blk, 0, stream>>>(Xbuf, rs);
    gemm_k<false, true, true, false><<<dim3(TQ / BM, NVOC / BN, 1), blk, 0, stream>>>(
        Xbuf, DM, head_w, (float*)d_out, NVOC, TQ, NVOC, DM,
        nullptr, rs, out_norm, head_b, nullptr, nullptr, 0);

    (void)in_sizes; (void)n_in; (void)out_size; (void)ws_size;
}

// Round 4
// 7320.857 us; speedup vs baseline: 1.2797x; 1.2797x over previous
//
#include <hip/hip_runtime.h>
#include <hip/hip_bf16.h>
#include <math.h>

// Problem dims (fixed by setup_inputs; n_layers is a device scalar -> hardcoded 8).
#define TQ    8192      // B*L tokens
#define DM    768       // model dim == ED
#define EMBD  512
#define NVOC  6400
#define LSEQ  2048
#define NBAT  4
#define NLAYER 8
#define DTR   48
#define CHUNK 64
#define NCH   (LSEQ/CHUNK)   // 32

// ---------------------------------------------------------------- GEMM (f32)
// C[M,N] = op(A) @ Bw(f32, KxN row-major), single-buffered LDS (round-2 loop:
// explicit dbuf regressed occupancy 21.6->11.8%, m99/m131 lesson reproduced).
// Microtile remap: thread (tx,ty) owns rows {4ty..+3, 64+4ty..+3} x cols
// {4tx..+3, 64+4tx..+3} -> LDS reads are float4 at [4tx]/[4tx+64]: 32 banks
// covered exactly twice (2-way = free, m136) vs old [8tx] 4-way conflict.
// GATHER: A rows gathered via rowidx (embedding).
// ASCALE: A element scaled by rscale[row]*cscale[k]  (fused rmsnorm).
// BIAS:   += bias[n].
// CONVSILU: epilogue applies silu(v*cw[col]+cb[col]) for col < DM (fused conv).
// K-split: blockIdx.z selects k-slice [z*kslice, (z+1)*kslice); C += z*slab.
#define BM 128
#define BN 128
#define BKK 16
#define LPAD 4
#define LDW (BM + LPAD)   // 132 floats; row stride 528B = 33*16B (b128-aligned)

template<bool GATHER, bool ASCALE, bool BIAS, bool CONVSILU>
__global__ __launch_bounds__(256)
void gemm_k(const float* __restrict__ A, int lda,
            const float* __restrict__ Bw,
            float* __restrict__ C, int ldc,
            int M, int N, int kslice,
            const int* __restrict__ rowidx,
            const float* __restrict__ rscale,
            const float* __restrict__ cscale,
            const float* __restrict__ bias,
            const float* __restrict__ cw, const float* __restrict__ cb,
            size_t slab)
{
    __shared__ float As[BKK][LDW];
    __shared__ float Bs[BKK][LDW];
    const int tid = threadIdx.x;
    const int tx = tid & 15;        // cols 4tx..+3 and 64+4tx..+3
    const int ty = tid >> 4;        // rows 4ty..+3 and 64+4ty..+3
    const int m0 = blockIdx.x * BM;
    const int n0 = blockIdx.y * BN;
    const int kbeg = blockIdx.z * kslice;
    float* Cz = C + (size_t)blockIdx.z * slab;

    float acc[8][8];
#pragma unroll
    for (int i = 0; i < 8; ++i)
#pragma unroll
        for (int j = 0; j < 8; ++j) acc[i][j] = 0.f;

    for (int k0 = kbeg; k0 < kbeg + kslice; k0 += BKK) {
        // stage A: thread (tx,ty) loads A[m0 + p*16 + ty][k0 + tx]
        // store bank = (4tx + 16p + ty) % 32 -> 2-way across the wave = free
#pragma unroll
        for (int p = 0; p < 8; ++p) {
            int r   = p * 16 + ty;          // 0..127
            int kg  = k0 + tx;
            long grow = GATHER ? (long)rowidx[m0 + r] : (long)(m0 + r);
            float v = A[grow * lda + kg];
            if (ASCALE) v *= rscale[m0 + r] * cscale[kg];
            As[tx][r] = v;
        }
        // stage B: 16x128 tile, consecutive lanes -> consecutive banks (free)
#pragma unroll
        for (int p = 0; p < 8; ++p) {
            int idx = p * 256 + tid;
            int kk = idx >> 7;              // 0..15
            int n  = idx & 127;
            int ng = n0 + n;
            Bs[kk][n] = (ng < N) ? Bw[(long)(k0 + kk) * N + ng] : 0.f;
        }
        __syncthreads();
#pragma unroll
        for (int kk = 0; kk < BKK; ++kk) {
            float a[8], b[8];
            *(float4*)&a[0] = *(const float4*)&As[kk][ty * 4];
            *(float4*)&a[4] = *(const float4*)&As[kk][ty * 4 + 64];
            *(float4*)&b[0] = *(const float4*)&Bs[kk][tx * 4];
            *(float4*)&b[4] = *(const float4*)&Bs[kk][tx * 4 + 64];
#pragma unroll
            for (int i = 0; i < 8; ++i)
#pragma unroll
                for (int j = 0; j < 8; ++j)
                    acc[i][j] = fmaf(a[i], b[j], acc[i][j]);
        }
        __syncthreads();
    }

    // epilogue (M multiple of 128; guard N only)
#pragma unroll
    for (int i = 0; i < 8; ++i) {
        int row = m0 + ((i < 4) ? (ty * 4 + i) : (64 + ty * 4 + i - 4));
#pragma unroll
        for (int j = 0; j < 8; ++j) {
            int col = n0 + ((j < 4) ? (tx * 4 + j) : (64 + tx * 4 + j - 4));
            if (col < N) {
                float v = acc[i][j];
                if (BIAS) v += bias[col];
                if (CONVSILU && col < DM) {
                    float xc = fmaf(v, cw[col], cb[col]);
                    v = xc / (1.f + expf(-xc));
                }
                Cz[(long)row * ldc + col] = v;
            }
        }
    }
}

// -------------------------------------------------- rmsnorm row scale factors
__global__ __launch_bounds__(256)
void rowscale_k(const float* __restrict__ X, float* __restrict__ rs)
{
    int row  = blockIdx.x * 4 + (threadIdx.x >> 6);
    int lane = threadIdx.x & 63;
    const float4* xr = (const float4*)(X + (size_t)row * DM);
    float s = 0.f;
#pragma unroll
    for (int e = 0; e < 3; ++e) {            // DM/4 = 192 = 3*64
        float4 v = xr[lane + e * 64];
        s = fmaf(v.x, v.x, s); s = fmaf(v.y, v.y, s);
        s = fmaf(v.z, v.z, s); s = fmaf(v.w, v.w, s);
    }
#pragma unroll
    for (int off = 32; off > 0; off >>= 1) s += __shfl_down(s, off);
    if (lane == 0) rs[row] = rsqrtf(s * (1.0f / DM) + 1e-6f);
}

// -------- dt_proj + softplus -> delta ; a = exp(delta*A) ; bx = delta*xi*B_t
// dbc comes as 4 K-split partial slabs: P[s][TQ][50], summed here.
__global__ __launch_bounds__(256)
void dtfuse_k(const float* __restrict__ part,
              const float* __restrict__ Wdt, const float* __restrict__ bdt,
              const float* __restrict__ XZ, const float* __restrict__ Alog,
              float* __restrict__ a_out, float* __restrict__ bx_out)
{
    __shared__ float ds[16][52];
    int t0 = blockIdx.x * 16;
    for (int idx = threadIdx.x; idx < 16 * 50; idx += 256) {
        int tt = idx / 50, c = idx - tt * 50;
        size_t o = (size_t)(t0 + tt) * 50 + c;
        ds[tt][c] = part[o] + part[o + (size_t)TQ * 50]
                  + part[o + 2 * (size_t)TQ * 50] + part[o + 3 * (size_t)TQ * 50];
    }
    __syncthreads();
    for (int e0 = 0; e0 < DM; e0 += 256) {
        int e = e0 + threadIdx.x;
        float bias = bdt[e];
        float acc[16];
#pragma unroll
        for (int tt = 0; tt < 16; ++tt) acc[tt] = bias;
        for (int k = 0; k < DTR; ++k) {
            float w = Wdt[(size_t)k * DM + e];
#pragma unroll
            for (int tt = 0; tt < 16; ++tt) acc[tt] = fmaf(ds[tt][k], w, acc[tt]);
        }
        float An = -expf(Alog[e]);             // A = -exp(A_log), N=1
#pragma unroll
        for (int tt = 0; tt < 16; ++tt) {
            float delta = log1pf(expf(acc[tt]));   // softplus
            float a  = expf(delta * An);
            float xi = XZ[(size_t)(t0 + tt) * 1536 + e];
            float Bv = ds[tt][48];
            a_out [(size_t)(t0 + tt) * DM + e] = a;
            bx_out[(size_t)(t0 + tt) * DM + e] = delta * xi * Bv;
        }
    }
}

// ------------------------------------------------ chunked exact scan (3 pass)
__global__ __launch_bounds__(256)
void scan1_k(const float* __restrict__ a, const float* __restrict__ bx,
             float* __restrict__ Ac, float* __restrict__ Sc)
{
    int gid = blockIdx.x * 256 + threadIdx.x;   // [0, NBAT*NCH*DM)
    int e  = gid % DM;
    int bc = gid / DM;
    int ch = bc % NCH, b = bc / NCH;
    size_t base = ((size_t)(b * LSEQ + ch * CHUNK)) * DM + e;
    float A = 1.f, S = 0.f;
    for (int i = 0; i < CHUNK; ++i) {
        float av = a[base + (size_t)i * DM];
        float bv = bx[base + (size_t)i * DM];
        S = fmaf(av, S, bv);
        A *= av;
    }
    Ac[gid] = A; Sc[gid] = S;
}

__global__ __launch_bounds__(256)
void scan2_k(const float* __restrict__ Ac, const float* __restrict__ Sc,
             float* __restrict__ H0)
{
    int gid = blockIdx.x * 256 + threadIdx.x;   // [0, NBAT*DM)
    int e = gid % DM, b = gid / DM;
    float h = 0.f;
    for (int ch = 0; ch < NCH; ++ch) {
        size_t i = ((size_t)(b * NCH + ch)) * DM + e;
        H0[i] = h;                               // exclusive chunk-entry state
        h = fmaf(Ac[i], h, Sc[i]);
    }
}

__global__ __launch_bounds__(256)
void scan3_k(const float* __restrict__ a, float* __restrict__ hs,
             const float* __restrict__ H0)
{
    int gid = blockIdx.x * 256 + threadIdx.x;
    int e  = gid % DM;
    int bc = gid / DM;
    int ch = bc % NCH, b = bc / NCH;
    size_t base = ((size_t)(b * LSEQ + ch * CHUNK)) * DM + e;
    float h = H0[gid];
    for (int i = 0; i < CHUNK; ++i) {
        size_t idx = base + (size_t)i * DM;
        h = fmaf(a[idx], h, hs[idx]);           // hs currently holds bx
        hs[idx] = h;                            // in-place -> hidden state
    }
}

// -------------------- y = (hs*C_t + D*xi) * silu(z), written into Y (=a buf)
__global__ __launch_bounds__(256)
void yfuse_k(const float* __restrict__ hs, const float* __restrict__ XZ,
             const float* __restrict__ part, const float* __restrict__ Dp,
             float* __restrict__ Y)
{
    int t = blockIdx.x;
    size_t o = (size_t)t * 50 + 49;
    float Cv = part[o] + part[o + (size_t)TQ * 50]
             + part[o + 2 * (size_t)TQ * 50] + part[o + 3 * (size_t)TQ * 50];
    for (int e = threadIdx.x; e < DM; e += 256) {
        float xi = XZ[(size_t)t * 1536 + e];
        float z  = XZ[(size_t)t * 1536 + DM + e];
        float y  = fmaf(hs[(size_t)t * DM + e], Cv, Dp[e] * xi);
        float sz = z / (1.f + expf(-z));
        Y[(size_t)t * DM + e] = y * sz;
    }
}

// ---------------------------------------------------------------------------
extern "C" void kernel_launch(void* const* d_in, const int* in_sizes, int n_in,
                              void* d_out, int out_size, void* d_ws, size_t ws_size,
                              hipStream_t stream)
{
    const int*   tokens   = (const int*)  d_in[0];
    // d_in[1] = n_layers (device scalar) -> hardcoded NLAYER
    const float* emb_tab  = (const float*)d_in[2];
    const float* emb_proj = (const float*)d_in[3];
    const float* norm_w   = (const float*)d_in[4];
    const float* in_proj  = (const float*)d_in[5];
    const float* conv_w   = (const float*)d_in[6];
    const float* conv_b   = (const float*)d_in[7];
    const float* x_proj   = (const float*)d_in[8];
    const float* dt_proj  = (const float*)d_in[9];
    const float* dt_b     = (const float*)d_in[10];
    const float* A_log    = (const float*)d_in[11];
    const float* D_param  = (const float*)d_in[12];
    const float* out_proj = (const float*)d_in[13];
    const float* out_norm = (const float*)d_in[14];
    const float* head_w   = (const float*)d_in[15];
    const float* head_b   = (const float*)d_in[16];

    // ws layout (~26.4 MB): all write-before-read each call
    float* Xbuf = (float*)d_ws;                     // TQ*DM
    float* rs   = Xbuf + (size_t)TQ * DM;           // TQ
    float* Ac   = rs + TQ;                          // NBAT*NCH*DM
    float* Sc   = Ac + (size_t)NBAT * NCH * DM;
    float* H0   = Sc + (size_t)NBAT * NCH * DM;

    // big scratch in d_out (f32 out = 209.7 MB; first ~107 MB used, all
    // write-before-read; head GEMM rewrites all of d_out at the end)
    float* XZ   = (float*)d_out;                    // TQ*1536
    float* Abuf = XZ + (size_t)TQ * 1536;           // TQ*DM (deltaA, later Y)
    float* BX   = Abuf + (size_t)TQ * DM;           // TQ*DM (bx -> hs in place)
    float* PART = BX + (size_t)TQ * DM;             // 4*TQ*50 (x_proj K-split)

    dim3 blk(256);

    // x = emb_table[tokens] @ emb_proj_w   (gathered GEMM, f32 out)
    gemm_k<true, false, false, false><<<dim3(TQ / BM, DM / BN, 1), blk, 0, stream>>>(
        emb_tab, EMBD, emb_proj, Xbuf, DM, TQ, DM, EMBD,
        tokens, nullptr, nullptr, nullptr, nullptr, nullptr, 0);

    for (int l = 0; l < NLAYER; ++l) {
        rowscale_k<<<TQ / 4, blk, 0, stream>>>(Xbuf, rs);
        // xz = rmsnorm(x)*norm_w @ in_proj_w, conv+silu fused on cols<DM
        gemm_k<false, true, false, true><<<dim3(TQ / BM, 1536 / BN, 1), blk, 0, stream>>>(
            Xbuf, DM, in_proj, XZ, 1536, TQ, 1536, DM,
            nullptr, rs, norm_w, nullptr, conv_w, conv_b, 0);
        // dbc partials = xi @ x_proj_w   (K split into 4 slices of 192)
        gemm_k<false, false, false, false><<<dim3(TQ / BM, 1, 4), blk, 0, stream>>>(
            XZ, 1536, x_proj, PART, 50, TQ, 50, DM / 4,
            nullptr, nullptr, nullptr, nullptr, nullptr, nullptr, (size_t)TQ * 50);
        dtfuse_k<<<TQ / 16, blk, 0, stream>>>(PART, dt_proj, dt_b, XZ, A_log, Abuf, BX);
        scan1_k<<<(NBAT * NCH * DM) / 256, blk, 0, stream>>>(Abuf, BX, Ac, Sc);
        scan2_k<<<(NBAT * DM) / 256, blk, 0, stream>>>(Ac, Sc, H0);
        scan3_k<<<(NBAT * NCH * DM) / 256, blk, 0, stream>>>(Abuf, BX, H0);
        yfuse_k<<<TQ, blk, 0, stream>>>(BX, XZ, PART, D_param, Abuf);
        // x' = y @ out_proj_w
        gemm_k<false, false, false, false><<<dim3(TQ / BM, DM / BN, 1), blk, 0, stream>>>(
            Abuf, DM, out_proj, Xbuf, DM, TQ, DM, DM,
            nullptr, nullptr, nullptr, nullptr, nullptr, nullptr, 0);
    }

    // out = rmsnorm(x)*out_norm_w @ head_w + head_b  (f32 out)
    rowscale_k<<<TQ / 4, blk, 0, stream>>>(Xbuf, rs);
    gemm_k<false, true, true, false><<<dim3(TQ / BM, NVOC / BN, 1), blk, 0, stream>>>(
        Xbuf, DM, head_w, (float*)d_out, NVOC, TQ, NVOC, DM,
        nullptr, rs, out_norm, head_b, nullptr, nullptr, 0);

    (void)in_sizes; (void)n_in; (void)out_size; (void)ws_size;
}

// Round 5
// 3636.674 us; speedup vs baseline: 2.5762x; 2.0131x over previous
//
#include <hip/hip_runtime.h>
#include <math.h>

// Problem dims (fixed by setup_inputs; n_layers is a device scalar -> hardcoded 8).
#define TQ    8192      // B*L tokens
#define DM    768       // model dim == ED
#define EMBD  512
#define NVOC  6400
#define LSEQ  2048
#define NBAT  4
#define NLAYER 8
#define DTR   48
#define CHUNK 64
#define NCH   (LSEQ/CHUNK)   // 32

typedef float f32x16  __attribute__((ext_vector_type(16)));
typedef short bf16x8  __attribute__((ext_vector_type(8)));
typedef short short4v __attribute__((ext_vector_type(4)));

static __device__ __forceinline__ short f2bf(float x) {
    unsigned u = __float_as_uint(x);
    unsigned r = (u + 0x7fffu + ((u >> 16) & 1u)) >> 16;   // RNE
    return (short)r;
}
static __device__ __forceinline__ float bf2f(short h) {
    return __uint_as_float(((unsigned)(unsigned short)h) << 16);
}
// exact 3-term split: hi+mid+lo = x * (1 +- 2^-24); subtractions are exact.
static __device__ __forceinline__ void split4(float4 v, short4v& h4, short4v& m4, short4v& l4)
{
    float x0 = v.x, x1 = v.y, x2 = v.z, x3 = v.w;
#define SPL(i, xx) { short h = f2bf(xx); float r = (xx) - bf2f(h);              \
                     short m = f2bf(r);  float r2 = r - bf2f(m);                \
                     short l = f2bf(r2); h4[i] = h; m4[i] = m; l4[i] = l; }
    SPL(0, x0) SPL(1, x1) SPL(2, x2) SPL(3, x3)
#undef SPL
}

// ------------------------------------------- split-bf16 MFMA GEMM (f32-accurate)
// C[M,N] = op(A) @ Bw(f32 KxN row-major), via 3-plane bf16 split + 6 MFMAs.
// Tile 128x128, K_STEP=32, 4 waves (2x2), wave = 2x2 mfma_f32_32x32x16_bf16.
// GATHER: A rows via rowidx. ASCALE: A *= rscale[row]*cscale[k] (fused rmsnorm).
// BIAS: += bias[n]. CONVSILU: v = silu(v*cw[col]+cb[col]) for col<DM.
// K-split: blockIdx.z -> k-slice [z*kslice,(z+1)*kslice), C += z*slab.
#define BM 128
#define BN 128
#define KS 32
#define ASTR 40   // shorts per LDS row: 32 data + 8 pad (80B, 16B-aligned reads)

template<bool GATHER, bool ASCALE, bool BIAS, bool CONVSILU>
__global__ __launch_bounds__(256)
void gemm_k(const float* __restrict__ A, int lda,
            const float* __restrict__ Bw,
            float* __restrict__ C, int ldc,
            int M, int N, int kslice,
            const int* __restrict__ rowidx,
            const float* __restrict__ rscale,
            const float* __restrict__ cscale,
            const float* __restrict__ bias,
            const float* __restrict__ cw, const float* __restrict__ cb,
            size_t slab)
{
    __shared__ __align__(16) short Ap[3][BM * ASTR];   // [plane][m][k] 10.24KB each
    __shared__ __align__(16) short Bp[3][BN * ASTR];   // [plane][n][k] (transposed)

    const int tid = threadIdx.x;
    const int ln  = tid & 63;
    const int wid = tid >> 6;            // 4 waves
    const int wr  = wid >> 1;            // wave row 0..1  (64 rows each)
    const int wc  = wid & 1;             // wave col 0..1  (64 cols each)
    const int m0  = blockIdx.x * BM;
    const int n0  = blockIdx.y * BN;
    const int kbeg = blockIdx.z * kslice;
    float* Cz = C + (size_t)blockIdx.z * slab;
    const bool fullN = (n0 + BN <= N);

    const int frow = ln & 31;            // row (A) / col (B) within 32x32 tile
    const int h8   = (ln >> 5) * 8;      // k sub-offset in shorts

    f32x16 acc[2][2];
#pragma unroll
    for (int i = 0; i < 2; ++i)
#pragma unroll
        for (int j = 0; j < 2; ++j) acc[i][j] = (f32x16)0.f;

    // staging decode
    const int am  = tid >> 3;            // A: base row 0..31 (+32p)
    const int ak4 = (tid & 7) * 4;       // A: k quad
    const int bkb = (tid >> 6) * 4;      // B: k group 0,4,8,12 (+16p)
    const int bn2 = (tid & 63) * 2;      // B: col pair

    for (int k0 = kbeg; k0 < kbeg + kslice; k0 += KS) {
        __syncthreads();                 // LDS safe to overwrite
        // ---- stage A: 128x32 f32 -> 3 bf16 planes [m][k]
#pragma unroll
        for (int p = 0; p < 4; ++p) {
            int m = am + p * 32;
            long grow = GATHER ? (long)rowidx[m0 + m] : (long)(m0 + m);
            float4 v = *(const float4*)&A[grow * lda + k0 + ak4];
            if (ASCALE) {
                float rsv = rscale[m0 + m];
                v.x *= rsv * cscale[k0 + ak4 + 0];
                v.y *= rsv * cscale[k0 + ak4 + 1];
                v.z *= rsv * cscale[k0 + ak4 + 2];
                v.w *= rsv * cscale[k0 + ak4 + 3];
            }
            short4v h4, m4, l4;
            split4(v, h4, m4, l4);
            int base = m * ASTR + ak4;
            *(short4v*)&Ap[0][base] = h4;
            *(short4v*)&Ap[1][base] = m4;
            *(short4v*)&Ap[2][base] = l4;
        }
        // ---- stage B: 32x128 f32 -> 3 bf16 planes [n][k] (register transpose)
#pragma unroll
        for (int p = 0; p < 2; ++p) {
            int kb = bkb + p * 16;
            float vv[4][2];
            if (fullN) {
#pragma unroll
                for (int i = 0; i < 4; ++i) {
                    float2 w = *(const float2*)&Bw[(long)(k0 + kb + i) * N + n0 + bn2];
                    vv[i][0] = w.x; vv[i][1] = w.y;
                }
            } else {
#pragma unroll
                for (int i = 0; i < 4; ++i)
#pragma unroll
                    for (int c = 0; c < 2; ++c) {
                        int ng = n0 + bn2 + c;
                        vv[i][c] = (ng < N) ? Bw[(long)(k0 + kb + i) * N + ng] : 0.f;
                    }
            }
#pragma unroll
            for (int c = 0; c < 2; ++c) {
                float4 t; t.x = vv[0][c]; t.y = vv[1][c]; t.z = vv[2][c]; t.w = vv[3][c];
                short4v h4, m4, l4;
                split4(t, h4, m4, l4);
                int base = (bn2 + c) * ASTR + kb;
                *(short4v*)&Bp[0][base] = h4;
                *(short4v*)&Bp[1][base] = m4;
                *(short4v*)&Bp[2][base] = l4;
            }
        }
        __syncthreads();
        // ---- compute: 2 k-groups x 2x2 tiles x 6 plane-combos
#pragma unroll
        for (int kg = 0; kg < 2; ++kg) {
            bf16x8 af[2][3], bf[2][3];
#pragma unroll
            for (int mt = 0; mt < 2; ++mt) {
                int off = (wr * 64 + mt * 32 + frow) * ASTR + kg * 16 + h8;
#pragma unroll
                for (int pl = 0; pl < 3; ++pl)
                    af[mt][pl] = *(const bf16x8*)&Ap[pl][off];
            }
#pragma unroll
            for (int nt = 0; nt < 2; ++nt) {
                int off = (wc * 64 + nt * 32 + frow) * ASTR + kg * 16 + h8;
#pragma unroll
                for (int pl = 0; pl < 3; ++pl)
                    bf[nt][pl] = *(const bf16x8*)&Bp[pl][off];
            }
#pragma unroll
            for (int mt = 0; mt < 2; ++mt)
#pragma unroll
                for (int nt = 0; nt < 2; ++nt) {
                    // small terms first (rounding), then dominant
                    acc[mt][nt] = __builtin_amdgcn_mfma_f32_32x32x16_bf16(af[mt][0], bf[nt][2], acc[mt][nt], 0, 0, 0);
                    acc[mt][nt] = __builtin_amdgcn_mfma_f32_32x32x16_bf16(af[mt][2], bf[nt][0], acc[mt][nt], 0, 0, 0);
                    acc[mt][nt] = __builtin_amdgcn_mfma_f32_32x32x16_bf16(af[mt][1], bf[nt][1], acc[mt][nt], 0, 0, 0);
                    acc[mt][nt] = __builtin_amdgcn_mfma_f32_32x32x16_bf16(af[mt][0], bf[nt][1], acc[mt][nt], 0, 0, 0);
                    acc[mt][nt] = __builtin_amdgcn_mfma_f32_32x32x16_bf16(af[mt][1], bf[nt][0], acc[mt][nt], 0, 0, 0);
                    acc[mt][nt] = __builtin_amdgcn_mfma_f32_32x32x16_bf16(af[mt][0], bf[nt][0], acc[mt][nt], 0, 0, 0);
                }
        }
    }

    // ---- epilogue: D mapping col=lane&31, row=(r&3)+8*(r>>2)+4*(lane>>5)
#pragma unroll
    for (int mt = 0; mt < 2; ++mt)
#pragma unroll
        for (int nt = 0; nt < 2; ++nt) {
            int col = n0 + wc * 64 + nt * 32 + (ln & 31);
            if (col < N) {
                int rbase = m0 + wr * 64 + mt * 32 + (ln >> 5) * 4;
                float cwv = 0.f, cbv = 0.f, bv = 0.f;
                if (BIAS) bv = bias[col];
                if (CONVSILU && col < DM) { cwv = cw[col]; cbv = cb[col]; }
#pragma unroll
                for (int r = 0; r < 16; ++r) {
                    int row = rbase + (r & 3) + (r >> 2) * 8;
                    float v = acc[mt][nt][r];
                    if (BIAS) v += bv;
                    if (CONVSILU && col < DM) {
                        float xc = fmaf(v, cwv, cbv);
                        v = xc / (1.f + expf(-xc));
                    }
                    Cz[(long)row * ldc + col] = v;
                }
            }
        }
}

// -------------------------------------------------- rmsnorm row scale factors
__global__ __launch_bounds__(256)
void rowscale_k(const float* __restrict__ X, float* __restrict__ rs)
{
    int row  = blockIdx.x * 4 + (threadIdx.x >> 6);
    int lane = threadIdx.x & 63;
    const float4* xr = (const float4*)(X + (size_t)row * DM);
    float s = 0.f;
#pragma unroll
    for (int e = 0; e < 3; ++e) {            // DM/4 = 192 = 3*64
        float4 v = xr[lane + e * 64];
        s = fmaf(v.x, v.x, s); s = fmaf(v.y, v.y, s);
        s = fmaf(v.z, v.z, s); s = fmaf(v.w, v.w, s);
    }
#pragma unroll
    for (int off = 32; off > 0; off >>= 1) s += __shfl_down(s, off);
    if (lane == 0) rs[row] = rsqrtf(s * (1.0f / DM) + 1e-6f);
}

// -------- dt_proj + softplus -> delta ; a = exp(delta*A) ; bx = delta*xi*B_t
// dbc comes as 4 K-split partial slabs: P[s][TQ][50], summed here.
__global__ __launch_bounds__(256)
void dtfuse_k(const float* __restrict__ part,
              const float* __restrict__ Wdt, const float* __restrict__ bdt,
              const float* __restrict__ XZ, const float* __restrict__ Alog,
              float* __restrict__ a_out, float* __restrict__ bx_out)
{
    __shared__ float ds[16][52];
    int t0 = blockIdx.x * 16;
    for (int idx = threadIdx.x; idx < 16 * 50; idx += 256) {
        int tt = idx / 50, c = idx - tt * 50;
        size_t o = (size_t)(t0 + tt) * 50 + c;
        ds[tt][c] = part[o] + part[o + (size_t)TQ * 50]
                  + part[o + 2 * (size_t)TQ * 50] + part[o + 3 * (size_t)TQ * 50];
    }
    __syncthreads();
    for (int e0 = 0; e0 < DM; e0 += 256) {
        int e = e0 + threadIdx.x;
        float bias = bdt[e];
        float acc[16];
#pragma unroll
        for (int tt = 0; tt < 16; ++tt) acc[tt] = bias;
        for (int k = 0; k < DTR; ++k) {
            float w = Wdt[(size_t)k * DM + e];
#pragma unroll
            for (int tt = 0; tt < 16; ++tt) acc[tt] = fmaf(ds[tt][k], w, acc[tt]);
        }
        float An = -expf(Alog[e]);             // A = -exp(A_log), N=1
#pragma unroll
        for (int tt = 0; tt < 16; ++tt) {
            float delta = log1pf(expf(acc[tt]));   // softplus
            float a  = expf(delta * An);
            float xi = XZ[(size_t)(t0 + tt) * 1536 + e];
            float Bv = ds[tt][48];
            a_out [(size_t)(t0 + tt) * DM + e] = a;
            bx_out[(size_t)(t0 + tt) * DM + e] = delta * xi * Bv;
        }
    }
}

// ------------------------------------------------ chunked exact scan (3 pass)
__global__ __launch_bounds__(256)
void scan1_k(const float* __restrict__ a, const float* __restrict__ bx,
             float* __restrict__ Ac, float* __restrict__ Sc)
{
    int gid = blockIdx.x * 256 + threadIdx.x;   // [0, NBAT*NCH*DM)
    int e  = gid % DM;
    int bc = gid / DM;
    int ch = bc % NCH, b = bc / NCH;
    size_t base = ((size_t)(b * LSEQ + ch * CHUNK)) * DM + e;
    float A = 1.f, S = 0.f;
    for (int i = 0; i < CHUNK; ++i) {
        float av = a[base + (size_t)i * DM];
        float bv = bx[base + (size_t)i * DM];
        S = fmaf(av, S, bv);
        A *= av;
    }
    Ac[gid] = A; Sc[gid] = S;
}

__global__ __launch_bounds__(256)
void scan2_k(const float* __restrict__ Ac, const float* __restrict__ Sc,
             float* __restrict__ H0)
{
    int gid = blockIdx.x * 256 + threadIdx.x;   // [0, NBAT*DM)
    int e = gid % DM, b = gid / DM;
    float h = 0.f;
    for (int ch = 0; ch < NCH; ++ch) {
        size_t i = ((size_t)(b * NCH + ch)) * DM + e;
        H0[i] = h;                               // exclusive chunk-entry state
        h = fmaf(Ac[i], h, Sc[i]);
    }
}

__global__ __launch_bounds__(256)
void scan3_k(const float* __restrict__ a, float* __restrict__ hs,
             const float* __restrict__ H0)
{
    int gid = blockIdx.x * 256 + threadIdx.x;
    int e  = gid % DM;
    int bc = gid / DM;
    int ch = bc % NCH, b = bc / NCH;
    size_t base = ((size_t)(b * LSEQ + ch * CHUNK)) * DM + e;
    float h = H0[gid];
    for (int i = 0; i < CHUNK; ++i) {
        size_t idx = base + (size_t)i * DM;
        h = fmaf(a[idx], h, hs[idx]);           // hs currently holds bx
        hs[idx] = h;                            // in-place -> hidden state
    }
}

// -------------------- y = (hs*C_t + D*xi) * silu(z), written into Y (=a buf)
__global__ __launch_bounds__(256)
void yfuse_k(const float* __restrict__ hs, const float* __restrict__ XZ,
             const float* __restrict__ part, const float* __restrict__ Dp,
             float* __restrict__ Y)
{
    int t = blockIdx.x;
    size_t o = (size_t)t * 50 + 49;
    float Cv = part[o] + part[o + (size_t)TQ * 50]
             + part[o + 2 * (size_t)TQ * 50] + part[o + 3 * (size_t)TQ * 50];
    for (int e = threadIdx.x; e < DM; e += 256) {
        float xi = XZ[(size_t)t * 1536 + e];
        float z  = XZ[(size_t)t * 1536 + DM + e];
        float y  = fmaf(hs[(size_t)t * DM + e], Cv, Dp[e] * xi);
        float sz = z / (1.f + expf(-z));
        Y[(size_t)t * DM + e] = y * sz;
    }
}

// ---------------------------------------------------------------------------
extern "C" void kernel_launch(void* const* d_in, const int* in_sizes, int n_in,
                              void* d_out, int out_size, void* d_ws, size_t ws_size,
                              hipStream_t stream)
{
    const int*   tokens   = (const int*)  d_in[0];
    // d_in[1] = n_layers (device scalar) -> hardcoded NLAYER
    const float* emb_tab  = (const float*)d_in[2];
    const float* emb_proj = (const float*)d_in[3];
    const float* norm_w   = (const float*)d_in[4];
    const float* in_proj  = (const float*)d_in[5];
    const float* conv_w   = (const float*)d_in[6];
    const float* conv_b   = (const float*)d_in[7];
    const float* x_proj   = (const float*)d_in[8];
    const float* dt_proj  = (const float*)d_in[9];
    const float* dt_b     = (const float*)d_in[10];
    const float* A_log    = (const float*)d_in[11];
    const float* D_param  = (const float*)d_in[12];
    const float* out_proj = (const float*)d_in[13];
    const float* out_norm = (const float*)d_in[14];
    const float* head_w   = (const float*)d_in[15];
    const float* head_b   = (const float*)d_in[16];

    // ws layout (~26.4 MB): all write-before-read each call
    float* Xbuf = (float*)d_ws;                     // TQ*DM
    float* rs   = Xbuf + (size_t)TQ * DM;           // TQ
    float* Ac   = rs + TQ;                          // NBAT*NCH*DM
    float* Sc   = Ac + (size_t)NBAT * NCH * DM;
    float* H0   = Sc + (size_t)NBAT * NCH * DM;

    // big scratch in d_out (f32 out = 209.7 MB; first ~107 MB used, all
    // write-before-read; head GEMM rewrites all of d_out at the end)
    float* XZ   = (float*)d_out;                    // TQ*1536
    float* Abuf = XZ + (size_t)TQ * 1536;           // TQ*DM (deltaA, later Y)
    float* BX   = Abuf + (size_t)TQ * DM;           // TQ*DM (bx -> hs in place)
    float* PART = BX + (size_t)TQ * DM;             // 4*TQ*50 (x_proj K-split)

    dim3 blk(256);

    // x = emb_table[tokens] @ emb_proj_w   (gathered GEMM, f32 out)
    gemm_k<true, false, false, false><<<dim3(TQ / BM, DM / BN, 1), blk, 0, stream>>>(
        emb_tab, EMBD, emb_proj, Xbuf, DM, TQ, DM, EMBD,
        tokens, nullptr, nullptr, nullptr, nullptr, nullptr, 0);

    for (int l = 0; l < NLAYER; ++l) {
        rowscale_k<<<TQ / 4, blk, 0, stream>>>(Xbuf, rs);
        // xz = rmsnorm(x)*norm_w @ in_proj_w, conv+silu fused on cols<DM
        gemm_k<false, true, false, true><<<dim3(TQ / BM, 1536 / BN, 1), blk, 0, stream>>>(
            Xbuf, DM, in_proj, XZ, 1536, TQ, 1536, DM,
            nullptr, rs, norm_w, nullptr, conv_w, conv_b, 0);
        // dbc partials = xi @ x_proj_w   (K split into 4 slices of 192)
        gemm_k<false, false, false, false><<<dim3(TQ / BM, 1, 4), blk, 0, stream>>>(
            XZ, 1536, x_proj, PART, 50, TQ, 50, DM / 4,
            nullptr, nullptr, nullptr, nullptr, nullptr, nullptr, (size_t)TQ * 50);
        dtfuse_k<<<TQ / 16, blk, 0, stream>>>(PART, dt_proj, dt_b, XZ, A_log, Abuf, BX);
        scan1_k<<<(NBAT * NCH * DM) / 256, blk, 0, stream>>>(Abuf, BX, Ac, Sc);
        scan2_k<<<(NBAT * DM) / 256, blk, 0, stream>>>(Ac, Sc, H0);
        scan3_k<<<(NBAT * NCH * DM) / 256, blk, 0, stream>>>(Abuf, BX, H0);
        yfuse_k<<<TQ, blk, 0, stream>>>(BX, XZ, PART, D_param, Abuf);
        // x' = y @ out_proj_w
        gemm_k<false, false, false, false><<<dim3(TQ / BM, DM / BN, 1), blk, 0, stream>>>(
            Abuf, DM, out_proj, Xbuf, DM, TQ, DM, DM,
            nullptr, nullptr, nullptr, nullptr, nullptr, nullptr, 0);
    }

    // out = rmsnorm(x)*out_norm_w @ head_w + head_b  (f32 out)
    rowscale_k<<<TQ / 4, blk, 0, stream>>>(Xbuf, rs);
    gemm_k<false, true, true, false><<<dim3(TQ / BM, NVOC / BN, 1), blk, 0, stream>>>(
        Xbuf, DM, head_w, (float*)d_out, NVOC, TQ, NVOC, DM,
        nullptr, rs, out_norm, head_b, nullptr, nullptr, 0);

    (void)in_sizes; (void)n_in; (void)out_size; (void)ws_size;
}

// Round 6
// 3028.353 us; speedup vs baseline: 3.0937x; 1.2009x over previous
//
#include <hip/hip_runtime.h>
#include <math.h>

// Problem dims (fixed by setup_inputs; n_layers is a device scalar -> hardcoded 8).
#define TQ    8192      // B*L tokens
#define DM    768       // model dim == ED
#define EMBD  512
#define NVOC  6400
#define LSEQ  2048
#define NBAT  4
#define NLAYER 8
#define DTR   48
#define CHUNK 64
#define NCH   (LSEQ/CHUNK)   // 32

typedef float f32x16  __attribute__((ext_vector_type(16)));
typedef short bf16x8  __attribute__((ext_vector_type(8)));
typedef short short4v __attribute__((ext_vector_type(4)));

static __device__ __forceinline__ short f2bf(float x) {
    unsigned u = __float_as_uint(x);
    unsigned r = (u + 0x7fffu + ((u >> 16) & 1u)) >> 16;   // RNE
    return (short)r;
}
static __device__ __forceinline__ float bf2f(short h) {
    return __uint_as_float(((unsigned)(unsigned short)h) << 16);
}
// exact 3-term split: hi+mid+lo = x * (1 +- 2^-24); subtractions are exact.
static __device__ __forceinline__ void split4(float4 v, short4v& h4, short4v& m4, short4v& l4)
{
    float x0 = v.x, x1 = v.y, x2 = v.z, x3 = v.w;
#define SPL(i, xx) { short h = f2bf(xx); float r = (xx) - bf2f(h);              \
                     short m = f2bf(r);  float r2 = r - bf2f(m);                \
                     short l = f2bf(r2); h4[i] = h; m4[i] = m; l4[i] = l; }
    SPL(0, x0) SPL(1, x1) SPL(2, x2) SPL(3, x3)
#undef SPL
}
static __device__ __forceinline__ void split1(float x, short& h, short& m, short& l)
{
    h = f2bf(x); float r = x - bf2f(h);
    m = f2bf(r); float r2 = r - bf2f(m);
    l = f2bf(r2);
}

#define BM 128
#define BN 128
#define KS 32
#define ASTR 40   // shorts per LDS row: 32 data + 8 pad (80B, 16B-aligned reads)

// ======================= plane-input GEMM (no split in hot loop) ============
// C[M,N](f32) = A @ B^T from pre-split bf16 planes:
//   Ap: 3 planes [M][K] (plane stride strideA shorts), lda = K
//   Bp: 3 planes [N][K] (pre-transposed; stride strideB), ldb = K
// 6-MFMA 3-plane combination == f32-accurate. Tile 128x128, KS=32, 4 waves.
// BIAS: += bias[n]. CONVSILU: col<DM -> v=silu(v*cw+cb), also write xi planes.
// K-split: blockIdx.z selects [z*kslice,(z+1)*kslice), C += z*slab.
template<bool BIAS, bool CONVSILU>
__global__ __launch_bounds__(256)
void gemmp_k(const short* __restrict__ Ap, int lda, size_t strideA,
             const short* __restrict__ Bp, int ldb, size_t strideB,
             float* __restrict__ C, int ldc,
             int M, int N, int kslice,
             const float* __restrict__ bias,
             const float* __restrict__ cw, const float* __restrict__ cb,
             short* __restrict__ xip, size_t strideXip,
             size_t slab)
{
    __shared__ __align__(16) short Asl[3][BM * ASTR];
    __shared__ __align__(16) short Bsl[3][BN * ASTR];

    const int tid = threadIdx.x;
    const int ln  = tid & 63;
    const int wid = tid >> 6;
    const int wr  = wid >> 1;
    const int wc  = wid & 1;
    const int m0  = blockIdx.x * BM;
    const int n0  = blockIdx.y * BN;
    const int kbeg = blockIdx.z * kslice;
    float* Cz = C + (size_t)blockIdx.z * slab;

    const int frow = ln & 31;
    const int h8   = (ln >> 5) * 8;

    f32x16 acc[2][2];
#pragma unroll
    for (int i = 0; i < 2; ++i)
#pragma unroll
        for (int j = 0; j < 2; ++j) acc[i][j] = (f32x16)0.f;

    for (int k0 = kbeg; k0 < kbeg + kslice; k0 += KS) {
        __syncthreads();
        bf16x8 av[2][3], bv[2][3];
#pragma unroll
        for (int i = 0; i < 2; ++i) {
            int u = tid + i * 256;
            int r = u >> 2, k8 = (u & 3) * 8;
            const short* ap = Ap + (size_t)(m0 + r) * lda + k0 + k8;
#pragma unroll
            for (int pl = 0; pl < 3; ++pl)
                av[i][pl] = *(const bf16x8*)(ap + pl * strideA);
            int nn = n0 + r;
            if (nn < N) {
                const short* bp = Bp + (size_t)nn * ldb + k0 + k8;
#pragma unroll
                for (int pl = 0; pl < 3; ++pl)
                    bv[i][pl] = *(const bf16x8*)(bp + pl * strideB);
            } else {
#pragma unroll
                for (int pl = 0; pl < 3; ++pl)
                    bv[i][pl] = (bf16x8)(short)0;
            }
        }
#pragma unroll
        for (int i = 0; i < 2; ++i) {
            int u = tid + i * 256;
            int r = u >> 2, k8 = (u & 3) * 8;
            int base = r * ASTR + k8;
#pragma unroll
            for (int pl = 0; pl < 3; ++pl) {
                *(bf16x8*)&Asl[pl][base] = av[i][pl];
                *(bf16x8*)&Bsl[pl][base] = bv[i][pl];
            }
        }
        __syncthreads();
#pragma unroll
        for (int kg = 0; kg < 2; ++kg) {
            bf16x8 af[2][3], bf[2][3];
#pragma unroll
            for (int mt = 0; mt < 2; ++mt) {
                int off = (wr * 64 + mt * 32 + frow) * ASTR + kg * 16 + h8;
#pragma unroll
                for (int pl = 0; pl < 3; ++pl)
                    af[mt][pl] = *(const bf16x8*)&Asl[pl][off];
            }
#pragma unroll
            for (int nt = 0; nt < 2; ++nt) {
                int off = (wc * 64 + nt * 32 + frow) * ASTR + kg * 16 + h8;
#pragma unroll
                for (int pl = 0; pl < 3; ++pl)
                    bf[nt][pl] = *(const bf16x8*)&Bsl[pl][off];
            }
#pragma unroll
            for (int mt = 0; mt < 2; ++mt)
#pragma unroll
                for (int nt = 0; nt < 2; ++nt) {
                    acc[mt][nt] = __builtin_amdgcn_mfma_f32_32x32x16_bf16(af[mt][0], bf[nt][2], acc[mt][nt], 0, 0, 0);
                    acc[mt][nt] = __builtin_amdgcn_mfma_f32_32x32x16_bf16(af[mt][2], bf[nt][0], acc[mt][nt], 0, 0, 0);
                    acc[mt][nt] = __builtin_amdgcn_mfma_f32_32x32x16_bf16(af[mt][1], bf[nt][1], acc[mt][nt], 0, 0, 0);
                    acc[mt][nt] = __builtin_amdgcn_mfma_f32_32x32x16_bf16(af[mt][0], bf[nt][1], acc[mt][nt], 0, 0, 0);
                    acc[mt][nt] = __builtin_amdgcn_mfma_f32_32x32x16_bf16(af[mt][1], bf[nt][0], acc[mt][nt], 0, 0, 0);
                    acc[mt][nt] = __builtin_amdgcn_mfma_f32_32x32x16_bf16(af[mt][0], bf[nt][0], acc[mt][nt], 0, 0, 0);
                }
        }
    }

    // epilogue: D mapping col=lane&31, row=(r&3)+8*(r>>2)+4*(lane>>5)
#pragma unroll
    for (int mt = 0; mt < 2; ++mt)
#pragma unroll
        for (int nt = 0; nt < 2; ++nt) {
            int col = n0 + wc * 64 + nt * 32 + (ln & 31);
            if (col < N) {
                int rbase = m0 + wr * 64 + mt * 32 + (ln >> 5) * 4;
                float cwv = 0.f, cbv = 0.f, bvs = 0.f;
                if (BIAS) bvs = bias[col];
                bool doconv = CONVSILU && (col < DM);
                if (doconv) { cwv = cw[col]; cbv = cb[col]; }
#pragma unroll
                for (int r = 0; r < 16; ++r) {
                    int row = rbase + (r & 3) + (r >> 2) * 8;
                    float v = acc[mt][nt][r];
                    if (BIAS) v += bvs;
                    if (doconv) {
                        float xc = fmaf(v, cwv, cbv);
                        v = xc / (1.f + expf(-xc));
                        short hh, mm, ll;
                        split1(v, hh, mm, ll);
                        size_t o = (size_t)row * DM + col;
                        xip[o] = hh;
                        xip[o + strideXip] = mm;
                        xip[o + 2 * strideXip] = ll;
                    }
                    Cz[(long)row * ldc + col] = v;
                }
            }
        }
}

// ======================= round-5 on-the-fly split GEMM (emb + head fallback)
template<bool GATHER, bool ASCALE, bool BIAS>
__global__ __launch_bounds__(256)
void gemm_k(const float* __restrict__ A, int lda,
            const float* __restrict__ Bw,
            float* __restrict__ C, int ldc,
            int M, int N, int K,
            const int* __restrict__ rowidx,
            const float* __restrict__ rscale,
            const float* __restrict__ cscale,
            const float* __restrict__ bias)
{
    __shared__ __align__(16) short Ap[3][BM * ASTR];
    __shared__ __align__(16) short Bp[3][BN * ASTR];

    const int tid = threadIdx.x;
    const int ln  = tid & 63;
    const int wid = tid >> 6;
    const int wr  = wid >> 1;
    const int wc  = wid & 1;
    const int m0  = blockIdx.x * BM;
    const int n0  = blockIdx.y * BN;
    const bool fullN = (n0 + BN <= N);

    const int frow = ln & 31;
    const int h8   = (ln >> 5) * 8;

    f32x16 acc[2][2];
#pragma unroll
    for (int i = 0; i < 2; ++i)
#pragma unroll
        for (int j = 0; j < 2; ++j) acc[i][j] = (f32x16)0.f;

    const int am  = tid >> 3;
    const int ak4 = (tid & 7) * 4;
    const int bkb = (tid >> 6) * 4;
    const int bn2 = (tid & 63) * 2;

    for (int k0 = 0; k0 < K; k0 += KS) {
        __syncthreads();
#pragma unroll
        for (int p = 0; p < 4; ++p) {
            int m = am + p * 32;
            long grow = GATHER ? (long)rowidx[m0 + m] : (long)(m0 + m);
            float4 v = *(const float4*)&A[grow * lda + k0 + ak4];
            if (ASCALE) {
                float rsv = rscale[m0 + m];
                v.x *= rsv * cscale[k0 + ak4 + 0];
                v.y *= rsv * cscale[k0 + ak4 + 1];
                v.z *= rsv * cscale[k0 + ak4 + 2];
                v.w *= rsv * cscale[k0 + ak4 + 3];
            }
            short4v h4, m4, l4;
            split4(v, h4, m4, l4);
            int base = m * ASTR + ak4;
            *(short4v*)&Ap[0][base] = h4;
            *(short4v*)&Ap[1][base] = m4;
            *(short4v*)&Ap[2][base] = l4;
        }
#pragma unroll
        for (int p = 0; p < 2; ++p) {
            int kb = bkb + p * 16;
            float vv[4][2];
            if (fullN) {
#pragma unroll
                for (int i = 0; i < 4; ++i) {
                    float2 w = *(const float2*)&Bw[(long)(k0 + kb + i) * N + n0 + bn2];
                    vv[i][0] = w.x; vv[i][1] = w.y;
                }
            } else {
#pragma unroll
                for (int i = 0; i < 4; ++i)
#pragma unroll
                    for (int c = 0; c < 2; ++c) {
                        int ng = n0 + bn2 + c;
                        vv[i][c] = (ng < N) ? Bw[(long)(k0 + kb + i) * N + ng] : 0.f;
                    }
            }
#pragma unroll
            for (int c = 0; c < 2; ++c) {
                float4 t; t.x = vv[0][c]; t.y = vv[1][c]; t.z = vv[2][c]; t.w = vv[3][c];
                short4v h4, m4, l4;
                split4(t, h4, m4, l4);
                int base = (bn2 + c) * ASTR + kb;
                *(short4v*)&Bp[0][base] = h4;
                *(short4v*)&Bp[1][base] = m4;
                *(short4v*)&Bp[2][base] = l4;
            }
        }
        __syncthreads();
#pragma unroll
        for (int kg = 0; kg < 2; ++kg) {
            bf16x8 af[2][3], bf[2][3];
#pragma unroll
            for (int mt = 0; mt < 2; ++mt) {
                int off = (wr * 64 + mt * 32 + frow) * ASTR + kg * 16 + h8;
#pragma unroll
                for (int pl = 0; pl < 3; ++pl)
                    af[mt][pl] = *(const bf16x8*)&Ap[pl][off];
            }
#pragma unroll
            for (int nt = 0; nt < 2; ++nt) {
                int off = (wc * 64 + nt * 32 + frow) * ASTR + kg * 16 + h8;
#pragma unroll
                for (int pl = 0; pl < 3; ++pl)
                    bf[nt][pl] = *(const bf16x8*)&Bp[pl][off];
            }
#pragma unroll
            for (int mt = 0; mt < 2; ++mt)
#pragma unroll
                for (int nt = 0; nt < 2; ++nt) {
                    acc[mt][nt] = __builtin_amdgcn_mfma_f32_32x32x16_bf16(af[mt][0], bf[nt][2], acc[mt][nt], 0, 0, 0);
                    acc[mt][nt] = __builtin_amdgcn_mfma_f32_32x32x16_bf16(af[mt][2], bf[nt][0], acc[mt][nt], 0, 0, 0);
                    acc[mt][nt] = __builtin_amdgcn_mfma_f32_32x32x16_bf16(af[mt][1], bf[nt][1], acc[mt][nt], 0, 0, 0);
                    acc[mt][nt] = __builtin_amdgcn_mfma_f32_32x32x16_bf16(af[mt][0], bf[nt][1], acc[mt][nt], 0, 0, 0);
                    acc[mt][nt] = __builtin_amdgcn_mfma_f32_32x32x16_bf16(af[mt][1], bf[nt][0], acc[mt][nt], 0, 0, 0);
                    acc[mt][nt] = __builtin_amdgcn_mfma_f32_32x32x16_bf16(af[mt][0], bf[nt][0], acc[mt][nt], 0, 0, 0);
                }
        }
    }
#pragma unroll
    for (int mt = 0; mt < 2; ++mt)
#pragma unroll
        for (int nt = 0; nt < 2; ++nt) {
            int col = n0 + wc * 64 + nt * 32 + (ln & 31);
            if (col < N) {
                int rbase = m0 + wr * 64 + mt * 32 + (ln >> 5) * 4;
                float bvs = BIAS ? bias[col] : 0.f;
#pragma unroll
                for (int r = 0; r < 16; ++r) {
                    int row = rbase + (r & 3) + (r >> 2) * 8;
                    float v = acc[mt][nt][r];
                    if (BIAS) v += bvs;
                    C[(long)row * ldc + col] = v;
                }
            }
        }
}

// ======================= weight presplit: W[K][N] f32 -> 3 planes [N][K] ====
__global__ __launch_bounds__(256)
void wsplit_k(const float* __restrict__ W, int K, int N,
              short* __restrict__ P, size_t pstride)
{
    __shared__ float Ws[64][65];
    int nt = blockIdx.x * 64, kt = blockIdx.y * 64;
    for (int u = threadIdx.x; u < 4096; u += 256) {
        int kk = u >> 6, nn = u & 63;
        Ws[kk][nn] = (nt + nn < N) ? W[(size_t)(kt + kk) * N + nt + nn] : 0.f;
    }
    __syncthreads();
    int nl = threadIdx.x >> 2, k16 = (threadIdx.x & 3) * 16;
    int n = nt + nl;
    if (n < N) {
        bf16x8 h[2], m[2], l[2];
#pragma unroll
        for (int j = 0; j < 16; ++j) {
            short hh, mm, ll;
            split1(Ws[k16 + j][nl], hh, mm, ll);
            h[j >> 3][j & 7] = hh; m[j >> 3][j & 7] = mm; l[j >> 3][j & 7] = ll;
        }
        size_t base = (size_t)n * K + kt + k16;
        *(bf16x8*)&P[base]              = h[0];
        *(bf16x8*)&P[base + 8]          = h[1];
        *(bf16x8*)&P[base + pstride]     = m[0];
        *(bf16x8*)&P[base + pstride + 8] = m[1];
        *(bf16x8*)&P[base + 2*pstride]     = l[0];
        *(bf16x8*)&P[base + 2*pstride + 8] = l[1];
    }
}

// ======================= rmsnorm rowscale + split planes ====================
__global__ __launch_bounds__(256)
void rowsplit_k(const float* __restrict__ X, const float* __restrict__ cscale,
                float* __restrict__ rs, short* __restrict__ P, size_t pstride)
{
    int row  = blockIdx.x * 4 + (threadIdx.x >> 6);
    int lane = threadIdx.x & 63;
    const float4* xr = (const float4*)(X + (size_t)row * DM);
    float4 v[3];
    float s = 0.f;
#pragma unroll
    for (int e = 0; e < 3; ++e) {
        v[e] = xr[lane + e * 64];
        s = fmaf(v[e].x, v[e].x, s); s = fmaf(v[e].y, v[e].y, s);
        s = fmaf(v[e].z, v[e].z, s); s = fmaf(v[e].w, v[e].w, s);
    }
#pragma unroll
    for (int off = 1; off < 64; off <<= 1) s += __shfl_xor(s, off);
    float rsv = rsqrtf(s * (1.0f / DM) + 1e-6f);
    if (lane == 0) rs[row] = rsv;
#pragma unroll
    for (int e = 0; e < 3; ++e) {
        int k = (lane + e * 64) * 4;
        float4 w = v[e];
        w.x *= rsv * cscale[k + 0]; w.y *= rsv * cscale[k + 1];
        w.z *= rsv * cscale[k + 2]; w.w *= rsv * cscale[k + 3];
        short4v h4, m4, l4;
        split4(w, h4, m4, l4);
        size_t o = (size_t)row * DM + k;
        *(short4v*)&P[o]               = h4;
        *(short4v*)&P[o + pstride]     = m4;
        *(short4v*)&P[o + 2 * pstride] = l4;
    }
}

// -------- dt_proj + softplus -> delta ; a = exp(delta*A) ; bx = delta*xi*B_t
__global__ __launch_bounds__(256)
void dtfuse_k(const float* __restrict__ part,
              const float* __restrict__ Wdt, const float* __restrict__ bdt,
              const float* __restrict__ XZ, const float* __restrict__ Alog,
              float* __restrict__ a_out, float* __restrict__ bx_out)
{
    __shared__ float ds[16][52];
    int t0 = blockIdx.x * 16;
    for (int idx = threadIdx.x; idx < 16 * 50; idx += 256) {
        int tt = idx / 50, c = idx - tt * 50;
        size_t o = (size_t)(t0 + tt) * 50 + c;
        ds[tt][c] = part[o] + part[o + (size_t)TQ * 50]
                  + part[o + 2 * (size_t)TQ * 50] + part[o + 3 * (size_t)TQ * 50];
    }
    __syncthreads();
    for (int e0 = 0; e0 < DM; e0 += 256) {
        int e = e0 + threadIdx.x;
        float bias = bdt[e];
        float acc[16];
#pragma unroll
        for (int tt = 0; tt < 16; ++tt) acc[tt] = bias;
        for (int k = 0; k < DTR; ++k) {
            float w = Wdt[(size_t)k * DM + e];
#pragma unroll
            for (int tt = 0; tt < 16; ++tt) acc[tt] = fmaf(ds[tt][k], w, acc[tt]);
        }
        float An = -expf(Alog[e]);
#pragma unroll
        for (int tt = 0; tt < 16; ++tt) {
            float delta = log1pf(expf(acc[tt]));
            float a  = expf(delta * An);
            float xi = XZ[(size_t)(t0 + tt) * 1536 + e];
            float Bv = ds[tt][48];
            a_out [(size_t)(t0 + tt) * DM + e] = a;
            bx_out[(size_t)(t0 + tt) * DM + e] = delta * xi * Bv;
        }
    }
}

// ------------------------------------------------ chunked exact scan (3 pass)
__global__ __launch_bounds__(256)
void scan1_k(const float* __restrict__ a, const float* __restrict__ bx,
             float* __restrict__ Ac, float* __restrict__ Sc)
{
    int gid = blockIdx.x * 256 + threadIdx.x;
    int e  = gid % DM;
    int bc = gid / DM;
    int ch = bc % NCH, b = bc / NCH;
    size_t base = ((size_t)(b * LSEQ + ch * CHUNK)) * DM + e;
    float A = 1.f, S = 0.f;
    for (int i = 0; i < CHUNK; ++i) {
        float av = a[base + (size_t)i * DM];
        float bv = bx[base + (size_t)i * DM];
        S = fmaf(av, S, bv);
        A *= av;
    }
    Ac[gid] = A; Sc[gid] = S;
}

__global__ __launch_bounds__(256)
void scan2_k(const float* __restrict__ Ac, const float* __restrict__ Sc,
             float* __restrict__ H0)
{
    int gid = blockIdx.x * 256 + threadIdx.x;
    int e = gid % DM, b = gid / DM;
    float h = 0.f;
    for (int ch = 0; ch < NCH; ++ch) {
        size_t i = ((size_t)(b * NCH + ch)) * DM + e;
        H0[i] = h;
        h = fmaf(Ac[i], h, Sc[i]);
    }
}

__global__ __launch_bounds__(256)
void scan3_k(const float* __restrict__ a, float* __restrict__ hs,
             const float* __restrict__ H0)
{
    int gid = blockIdx.x * 256 + threadIdx.x;
    int e  = gid % DM;
    int bc = gid / DM;
    int ch = bc % NCH, b = bc / NCH;
    size_t base = ((size_t)(b * LSEQ + ch * CHUNK)) * DM + e;
    float h = H0[gid];
    for (int i = 0; i < CHUNK; ++i) {
        size_t idx = base + (size_t)i * DM;
        h = fmaf(a[idx], h, hs[idx]);
        hs[idx] = h;
    }
}

// ------------- y = (hs*C_t + D*xi) * silu(z)  -> 3 bf16 planes (out_proj A)
__global__ __launch_bounds__(256)
void yfuse_k(const float* __restrict__ hs, const float* __restrict__ XZ,
             const float* __restrict__ part, const float* __restrict__ Dp,
             short* __restrict__ Yp, size_t pstride)
{
    int t = blockIdx.x;
    size_t o = (size_t)t * 50 + 49;
    float Cv = part[o] + part[o + (size_t)TQ * 50]
             + part[o + 2 * (size_t)TQ * 50] + part[o + 3 * (size_t)TQ * 50];
    for (int e = threadIdx.x; e < DM; e += 256) {
        float xi = XZ[(size_t)t * 1536 + e];
        float z  = XZ[(size_t)t * 1536 + DM + e];
        float y  = fmaf(hs[(size_t)t * DM + e], Cv, Dp[e] * xi);
        float sz = z / (1.f + expf(-z));
        float yo = y * sz;
        short hh, mm, ll;
        split1(yo, hh, mm, ll);
        size_t po = (size_t)t * DM + e;
        Yp[po] = hh;
        Yp[po + pstride] = mm;
        Yp[po + 2 * pstride] = ll;
    }
}

// ---------------------------------------------------------------------------
extern "C" void kernel_launch(void* const* d_in, const int* in_sizes, int n_in,
                              void* d_out, int out_size, void* d_ws, size_t ws_size,
                              hipStream_t stream)
{
    const int*   tokens   = (const int*)  d_in[0];
    // d_in[1] = n_layers (device scalar) -> hardcoded NLAYER
    const float* emb_tab  = (const float*)d_in[2];
    const float* emb_proj = (const float*)d_in[3];
    const float* norm_w   = (const float*)d_in[4];
    const float* in_proj  = (const float*)d_in[5];
    const float* conv_w   = (const float*)d_in[6];
    const float* conv_b   = (const float*)d_in[7];
    const float* x_proj   = (const float*)d_in[8];
    const float* dt_proj  = (const float*)d_in[9];
    const float* dt_b     = (const float*)d_in[10];
    const float* A_log    = (const float*)d_in[11];
    const float* D_param  = (const float*)d_in[12];
    const float* out_proj = (const float*)d_in[13];
    const float* out_norm = (const float*)d_in[14];
    const float* head_w   = (const float*)d_in[15];
    const float* head_b   = (const float*)d_in[16];

    // ----- ws layout (base 26.4 MB, known-safe): all write-before-read
    float* Xbuf = (float*)d_ws;                     // TQ*DM
    float* rs   = Xbuf + (size_t)TQ * DM;           // TQ
    float* Ac   = rs + TQ;                          // NBAT*NCH*DM
    float* Sc   = Ac + (size_t)NBAT * NCH * DM;
    float* H0   = Sc + (size_t)NBAT * NCH * DM;
    short* wsEnd = (short*)(H0 + (size_t)NBAT * NCH * DM);

    // ----- d_out scratch (209.7 MB total; head GEMM rewrites all of it last)
    float* XZ   = (float*)d_out;                    // TQ*1536 f32
    float* Abuf = XZ + (size_t)TQ * 1536;           // TQ*DM (deltaA)
    float* BX   = Abuf + (size_t)TQ * DM;           // TQ*DM (bx -> hs)
    float* PART = BX + (size_t)TQ * DM;             // 4*TQ*50
    short* SP   = (short*)(PART + (size_t)4 * TQ * 50);   // plane region
    // plane buffers (3 planes each, contiguous)
    const size_t sWEP = (size_t)768 * EMBD;         // emb_proj planes [768][512]
    const size_t sWIP = (size_t)1536 * DM;          // in_proj planes [1536][768]
    const size_t sWXP = (size_t)50 * DM;            // x_proj planes  [50][768]
    const size_t sWOP = (size_t)DM * DM;            // out_proj       [768][768]
    const size_t sACT = (size_t)TQ * DM;            // activation planes [TQ][768]
    short* WEPp = SP;
    short* WIPp = WEPp + 3 * sWEP;
    short* WXPp = WIPp + 3 * sWIP;
    short* WOPp = WXPp + 3 * sWXP;
    short* XIp  = WOPp + 3 * sWOP;                  // xi planes
    short* XNp  = XIp + 3 * sACT;                   // xnorm planes / y planes

    // head fast path needs xnorm planes + head planes outside d_out
    const size_t sWHD = (size_t)NVOC * DM;
    const size_t WS_BASE = (size_t)TQ * DM * 4 + TQ * 4 + 3 * (size_t)NBAT * NCH * DM * 4;
    const size_t WS_NEED = WS_BASE + 3 * sACT * 2 + 3 * sWHD * 2;
    const bool wsok = (ws_size >= WS_NEED);
    short* XNhp = wsok ? wsEnd : XNp;
    short* WHDp = wsok ? (wsEnd + 3 * sACT) : (short*)nullptr;

    dim3 blk(256);

    // ----- presplit weights (once per call)
    wsplit_k<<<dim3(12, 8),  blk, 0, stream>>>(emb_proj, EMBD, DM,   WEPp, sWEP);
    wsplit_k<<<dim3(24, 12), blk, 0, stream>>>(in_proj,  DM, 1536,   WIPp, sWIP);
    wsplit_k<<<dim3(1, 12),  blk, 0, stream>>>(x_proj,   DM, 50,     WXPp, sWXP);
    wsplit_k<<<dim3(12, 12), blk, 0, stream>>>(out_proj, DM, DM,     WOPp, sWOP);
    if (wsok)
        wsplit_k<<<dim3(100, 12), blk, 0, stream>>>(head_w, DM, NVOC, WHDp, sWHD);

    // ----- x = emb_table[tokens] @ emb_proj (gather + on-the-fly split; runs once)
    gemm_k<true, false, false><<<dim3(TQ / BM, DM / BN), blk, 0, stream>>>(
        emb_tab, EMBD, emb_proj, Xbuf, DM, TQ, DM, EMBD,
        tokens, nullptr, nullptr, nullptr);

    for (int l = 0; l < NLAYER; ++l) {
        rowsplit_k<<<TQ / 4, blk, 0, stream>>>(Xbuf, norm_w, rs, XNp, sACT);
        // xz = rmsnorm(x)*norm_w @ in_proj; conv+silu fused; writes XZ f32 + xi planes
        gemmp_k<false, true><<<dim3(TQ / BM, 1536 / BN), blk, 0, stream>>>(
            XNp, DM, sACT, WIPp, DM, sWIP, XZ, 1536, TQ, 1536, DM,
            nullptr, conv_w, conv_b, XIp, sACT, 0);
        // dbc partials = xi @ x_proj  (K split x4)
        gemmp_k<false, false><<<dim3(TQ / BM, 1, 4), blk, 0, stream>>>(
            XIp, DM, sACT, WXPp, DM, sWXP, PART, 50, TQ, 50, DM / 4,
            nullptr, nullptr, nullptr, nullptr, 0, (size_t)TQ * 50);
        dtfuse_k<<<TQ / 16, blk, 0, stream>>>(PART, dt_proj, dt_b, XZ, A_log, Abuf, BX);
        scan1_k<<<(NBAT * NCH * DM) / 256, blk, 0, stream>>>(Abuf, BX, Ac, Sc);
        scan2_k<<<(NBAT * DM) / 256, blk, 0, stream>>>(Ac, Sc, H0);
        scan3_k<<<(NBAT * NCH * DM) / 256, blk, 0, stream>>>(Abuf, BX, H0);
        // y planes into XNp (xnorm planes dead after in_proj)
        yfuse_k<<<TQ, blk, 0, stream>>>(BX, XZ, PART, D_param, XNp, sACT);
        // x' = y @ out_proj
        gemmp_k<false, false><<<dim3(TQ / BM, DM / BN), blk, 0, stream>>>(
            XNp, DM, sACT, WOPp, DM, sWOP, Xbuf, DM, TQ, DM, DM,
            nullptr, nullptr, nullptr, nullptr, 0, 0);
    }

    // ----- head
    rowsplit_k<<<TQ / 4, blk, 0, stream>>>(Xbuf, out_norm, rs, XNhp, sACT);
    if (wsok) {
        gemmp_k<true, false><<<dim3(TQ / BM, NVOC / BN), blk, 0, stream>>>(
            XNhp, DM, sACT, WHDp, DM, sWHD, (float*)d_out, NVOC, TQ, NVOC, DM,
            head_b, nullptr, nullptr, nullptr, 0, 0);
    } else {
        gemm_k<false, true, true><<<dim3(TQ / BM, NVOC / BN), blk, 0, stream>>>(
            Xbuf, DM, head_w, (float*)d_out, NVOC, TQ, NVOC, DM,
            nullptr, rs, out_norm, head_b);
    }

    (void)in_sizes; (void)n_in; (void)out_size;
}